// Round 5
// baseline (413.250 us; speedup 1.0000x reference)
//
#include <hip/hip_runtime.h>
#include <stdint.h>

// Self-attention, B=8, S=2048, D=1024, fp32 in/out, bf16 MFMA compute.
//
// Pipeline:
//   1. k_cvt: x -> xb (bf16), zero l;  k_cvt3: Wq/Wk/Wv -> Wb
//   2. k_qkv3 (z=0,1): Q/K = xb @ W^T + b   (z=2): Vt = (xb @ Wv^T + bv)^T
//   3. k_scores: U = exp((Q @ K^T)/32) bf16 + atomic per-row sums into l
//   4. k_pv   : out = (U @ Vt^T) * (1/l[row])  (fp32 out)
//
// R10: 128x128-tile / 4-wave / BK=32 / ring-3 core for 2 blocks/CU.
//  R9 post-mortem: conflicts fixed (9.96M->524K) but time flat -> LDS reads
//  were not critical. MfmaUtil 38 + VALUBusy 19 => ~43% stall: single
//  8-wave block per CU means every barrier stalls ALL resident waves.
//  Fix via cross-block TLP (m97/m114 mechanism): 48 KB LDS + ~135 regs
//  -> 2 co-resident blocks/CU; each SIMD hosts one wave of each block, so
//  one block's barrier wait is covered by the other's MFMA stream.
//  - ring-3 x 16 KB (A 128x32 + B 128x32 per tile), counted vmcnt(4):
//    stage tile t+2 in phase 2 (after B1 => all tile t-1 reads retired;
//    buffer (t+2)%3 == (t-1)%3 is dead); vmcnt(4) confirms tile t+1 before
//    B2 (publish). Tail: vmcnt(0) when t+2>=T. Never drains in steady state.
//  - XOR chunk swizzle kept from R9: read slot quad^((lr>>1)&3), staged
//    inverse (t&3)^((rowS>>1)&3); rows r,r+64 share the key (64%4==0).
//  - Per-wave 64x64 output, acc[4][4] -> epilogues are the verified R7 code
//    verbatim (EPI0/1 LDS repack 128x136, EPI2, EPI3 transposed Vt).
//  - Kept: batch<->XCD pinning, z-slowest W-pinning, l zeroed in k_cvt,
//    exp-sum softmax (|s|<=|q||k|/32, no max subtraction).
//
// ws layout:
//   [0,       33.5M)  Q        16384x1024 bf16
//   [33.5M,   67.1M)  K        16384x1024 bf16
//   [67.1M,  100.7M)  Vt       8 x 1024x2048 bf16
//   [100.7M, 167.8M)  U        8 x 2048x2048 bf16  (first half aliases xb)
//   [167.8M, 174.1M)  Wb       3 x 1024x1024 bf16
//   [174.1M, ...)     l        16384 fp32 (attn row sums, atomic)

typedef __bf16 bf16_t;
typedef __bf16 bf16x8 __attribute__((ext_vector_type(8)));
typedef __bf16 bf16x4 __attribute__((ext_vector_type(4)));
typedef float f32x4 __attribute__((ext_vector_type(4)));

__device__ __forceinline__ void gload_lds16(const bf16_t* g, bf16_t* l) {
    __builtin_amdgcn_global_load_lds((const __attribute__((address_space(1))) void*)g,
                                     (__attribute__((address_space(3))) void*)l,
                                     16, 0, 0);
}

// ---------------------------------------------------------------------------
// Core GEMM: C[M,N] = A[M,K] @ B[N,K]^T, bf16 row-major K-contiguous.
// Tile 128x128, BK=32, 256 threads (4 waves 2x2), per-wave 64x64 output
// (acc[4][4] of 16x16x32 MFMA).
// lds: caller-provided 24576 bf16 (48 KiB): 3 ring buffers of 8192 elems
// (A 128x32 = 4096 + B 128x32 = 4096). Epilogue (EPI 0/1) reuses it as
// a 128x136 repack buffer (17408 elems).
// EPI: 0 = (+bias[col]) -> bf16 coalesced stores
//      1 = exp(acc*scale) -> bf16 stores + atomic row sums into aux
//      2 = acc*(1/aux[row]) -> fp32 direct stores
//      3 = (+bias[col]) -> bf16 TRANSPOSED into Vt[b][col][row]
// ---------------------------------------------------------------------------
template <int EPI, int LDA, int LDB>
__device__ __forceinline__ void gemm_bt_core(
    bf16_t* __restrict__ lds,
    const bf16_t* __restrict__ A,
    const bf16_t* __restrict__ B,
    bf16_t* __restrict__ Cb, float* __restrict__ Cf, int ldc,
    float* __restrict__ aux, float scale, int K,
    int m0, int n0)
{
    const int t    = threadIdx.x;         // 0..255
    const int lane = t & 63;
    const int wave = t >> 6;              // 0..3
    const int wm   = wave >> 1;           // 0..1
    const int wn   = wave & 1;            // 0..1
    const int lr   = lane & 15;
    const int quad = lane >> 4;

    // Staging: thread t owns two 16B slots per 128x32 tile (rows rowS and
    // rowS+64). Physical slot s of row r holds chunk s ^ ((r>>1)&3); rows
    // r and r+64 share the key (64 % 4 == 0), so one swizzle constant works.
    const int rowS = t >> 2;                       // 0..63
    const int qS   = (t & 3) ^ ((rowS >> 1) & 3);
    const bf16_t* Ag = A + (size_t)(m0 + rowS) * LDA + qS * 8;
    const bf16_t* Bg = B + (size_t)(n0 + rowS) * LDB + qS * 8;
    const int dst0 = t * 8;                        // = rowS*32 + (t&3)*8

    // Fragment reads: slot = quad ^ ((lr>>1)&3) -> per-16-lane start classes
    // (row&1)*4 + slot cover all 8 16B-classes twice -> 2-way only (free).
    const int ko   = (quad ^ ((lr >> 1) & 3)) * 8;
    const int aoff = (wm * 64 + lr) * 32 + ko;     // af[i] at +512*i
    const int boff = (wn * 64 + lr) * 32 + ko;     // bfr[j] at +512*j

    f32x4 acc[4][4];
#pragma unroll
    for (int i = 0; i < 4; i++)
#pragma unroll
        for (int j = 0; j < 4; j++) acc[i][j] = (f32x4){0.f, 0.f, 0.f, 0.f};

    const int T = K >> 5;   // K32-steps (>= 3)

    // Prologue: stage tiles 0,1 (8 loads/thread), confirm tile 0.
#pragma unroll
    for (int tt = 0; tt < 2; ++tt) {
        bf16_t* Ab = lds + tt * 8192;
        const int kt = tt * 32;
        gload_lds16(Ag + kt,                    Ab + dst0);
        gload_lds16(Ag + kt + (size_t)64 * LDA, Ab + 2048 + dst0);
        gload_lds16(Bg + kt,                    Ab + 4096 + dst0);
        gload_lds16(Bg + kt + (size_t)64 * LDB, Ab + 6144 + dst0);
    }
    asm volatile("s_waitcnt vmcnt(4)" ::: "memory");
    __builtin_amdgcn_s_barrier();
    __builtin_amdgcn_sched_barrier(0);

    int buf = 0;                 // tk % 3
    int bufn = 2;                // (tk+2) % 3
    for (int tk = 0; tk < T; ++tk) {
        const bf16_t* Ab = lds + buf * 8192;
        const bf16_t* Bb = Ab + 4096;
        bf16x8 af[4], bfr[4];
        // ---- phase 1: read af[0..1] + bfr[0..3], compute i=0,1
        af[0] = *(const bf16x8*)(Ab + aoff);
        af[1] = *(const bf16x8*)(Ab + aoff + 512);
#pragma unroll
        for (int j = 0; j < 4; ++j)
            bfr[j] = *(const bf16x8*)(Bb + boff + 512 * j);
        __builtin_amdgcn_s_barrier();              // B_{t,1}
        __builtin_amdgcn_sched_barrier(0);
        __builtin_amdgcn_s_setprio(1);
#pragma unroll
        for (int i = 0; i < 2; ++i)
#pragma unroll
            for (int j = 0; j < 4; ++j)
                acc[i][j] = __builtin_amdgcn_mfma_f32_16x16x32_bf16(af[i], bfr[j], acc[i][j], 0, 0, 0);
        __builtin_amdgcn_s_setprio(0);
        // ---- phase 2: read af[2..3], stage tile t+2, compute i=2,3
        af[2] = *(const bf16x8*)(Ab + aoff + 1024);
        af[3] = *(const bf16x8*)(Ab + aoff + 1536);
        if (tk + 2 < T) {
            bf16_t* An = lds + bufn * 8192;        // == buffer of tile t-1 (dead)
            const int kt = (tk + 2) * 32;
            gload_lds16(Ag + kt,                    An + dst0);
            gload_lds16(Ag + kt + (size_t)64 * LDA, An + 2048 + dst0);
            gload_lds16(Bg + kt,                    An + 4096 + dst0);
            gload_lds16(Bg + kt + (size_t)64 * LDB, An + 6144 + dst0);
            asm volatile("s_waitcnt vmcnt(4)" ::: "memory");  // tile t+1 confirmed
        } else {
            asm volatile("s_waitcnt vmcnt(0)" ::: "memory");
        }
        __builtin_amdgcn_s_barrier();              // B_{t,2}: tile t+1 published
        __builtin_amdgcn_sched_barrier(0);
        __builtin_amdgcn_s_setprio(1);
#pragma unroll
        for (int i = 2; i < 4; ++i)
#pragma unroll
            for (int j = 0; j < 4; ++j)
                acc[i][j] = __builtin_amdgcn_mfma_f32_16x16x32_bf16(af[i], bfr[j], acc[i][j], 0, 0, 0);
        __builtin_amdgcn_s_setprio(0);
        buf  = (buf == 2) ? 0 : buf + 1;
        bufn = (bufn == 2) ? 0 : bufn + 1;
    }

    // Epilogue. C/D layout: col = lane&15, row = quad*4 + reg. (R7-verified)
    if (EPI == 0 || EPI == 1) {
        // stage to LDS (row stride 136), then 16-B coalesced stores
        __syncthreads();
#pragma unroll
        for (int j = 0; j < 4; j++) {
            const int col = wn * 64 + j * 16 + lr;
            const float bv = (EPI == 0) ? aux[n0 + col] : 0.f;
#pragma unroll
            for (int i = 0; i < 4; i++) {
                const int row = wm * 64 + i * 16 + quad * 4;
#pragma unroll
                for (int r = 0; r < 4; r++) {
                    float v = (EPI == 0) ? (acc[i][j][r] + bv)
                                         : __expf(acc[i][j][r] * scale);
                    lds[(row + r) * 136 + col] = (__bf16)v;
                }
            }
        }
        __syncthreads();
        const int lr2  = t >> 1;       // row 0..127
        const int half = t & 1;        // col half
        float part = 0.f;
#pragma unroll
        for (int c8 = 0; c8 < 8; c8++) {
            const int col0 = half * 64 + c8 * 8;
            bf16x8 v = *(const bf16x8*)(lds + lr2 * 136 + col0);
            *(bf16x8*)(Cb + (size_t)(m0 + lr2) * ldc + n0 + col0) = v;
            if (EPI == 1) {
#pragma unroll
                for (int e = 0; e < 8; e++) part += (float)v[e];
            }
        }
        if (EPI == 1) {
            part += __shfl_xor(part, 1);
            if (half == 0) atomicAdd(aux + m0 + lr2, part);
        }
    } else if (EPI == 2) {
#pragma unroll
        for (int i = 0; i < 4; i++) {
            const int row = m0 + wm * 64 + i * 16 + quad * 4;
#pragma unroll
            for (int r = 0; r < 4; r++) {
                const float s = 1.0f / aux[row + r];
                float* crow = Cf + (size_t)(row + r) * ldc + n0 + wn * 64 + lr;
#pragma unroll
                for (int j = 0; j < 4; j++)
                    crow[j * 16] = acc[i][j][r] * s;
            }
        }
    } else {
        // EPI 3: transposed write into Vt[b][col][row], rows global = b*2048+s
#pragma unroll
        for (int j = 0; j < 4; j++) {
            const int col = n0 + wn * 64 + j * 16 + lr;      // d index
            const float bv = aux[col];
#pragma unroll
            for (int i = 0; i < 4; i++) {
                const int rowg = m0 + wm * 64 + i * 16 + quad * 4;  // global s
                const int b    = rowg >> 11;
                const int s    = rowg & 2047;
                bf16x4 p = { (__bf16)(acc[i][j][0] + bv), (__bf16)(acc[i][j][1] + bv),
                             (__bf16)(acc[i][j][2] + bv), (__bf16)(acc[i][j][3] + bv) };
                *(bf16x4*)(Cb + ((size_t)b << 21) + ((size_t)col << 11) + s) = p;
            }
        }
    }
}

// --------------------------- kernel wrappers -------------------------------

// Q/K/Vt projection, grid (8,128,3). xcd = lid&7; within an XCD, x' (weight
// n-tile) fast, y' (A-strip) middle, z' (which matrix) slowest -> W_z (2 MB)
// L2-pinned per phase, xb strips read via L2/L3.
__global__ __launch_bounds__(256, 2) void k_qkv3(
    const bf16_t* __restrict__ xb, const bf16_t* __restrict__ Wb,
    bf16_t* __restrict__ Q, bf16_t* __restrict__ Vt,
    const float* __restrict__ bq, const float* __restrict__ bk,
    const float* __restrict__ bv)
{
    __shared__ bf16_t lds[24576];
    const int lid  = blockIdx.x + 8 * blockIdx.y + 1024 * blockIdx.z;
    const int xcd  = lid & 7;
    const int slot = lid >> 3;          // 0..383
    const int z    = slot >> 7;         // 0..2, slowest
    const int rem  = slot & 127;
    const int xt   = rem & 7;           // fast
    const int yt   = xcd * 16 + (rem >> 3);
    if (z < 2) {
        float* bias = (float*)((z == 0) ? bq : bk);
        gemm_bt_core<0, 1024, 1024>(lds, xb, Wb + (size_t)z * 1048576,
                                    Q + (size_t)z * 16777216, nullptr, 1024,
                                    bias, 0.f, 1024, yt * 128, xt * 128);
    } else {
        gemm_bt_core<3, 1024, 1024>(lds, xb, Wb + (size_t)2 * 1048576,
                                    Vt, nullptr, 0,
                                    (float*)bv, 0.f, 1024, yt * 128, xt * 128);
    }
}

// scores, grid (16,16,8): batch = lid&7 == XCD -> per-XCD working set is one
// batch's K matrix (4 MB = L2). Within XCD: x-tile fast (K sweep).
__global__ __launch_bounds__(256, 2) void k_scores(
    const bf16_t* __restrict__ Q, const bf16_t* __restrict__ Km,
    bf16_t* __restrict__ U, float* __restrict__ l)
{
    __shared__ bf16_t lds[24576];
    const int lid = blockIdx.x + 16 * blockIdx.y + 256 * blockIdx.z;
    const int b   = lid & 7;
    const int si  = lid >> 3;           // 0..255
    const int xt  = si & 15;
    const int yt  = si >> 4;
    gemm_bt_core<1, 1024, 1024>(lds, Q + (size_t)b * 2048 * 1024,
                                Km + (size_t)b * 2048 * 1024,
                                U + (size_t)b * 2048 * 2048, nullptr, 2048,
                                l + b * 2048, 0.03125f, 1024,
                                yt * 128, xt * 128);
}

// PV, grid (8,16,8): batch = lid&7 == XCD -> per-XCD working set is one
// batch's Vt (4 MB = L2).
__global__ __launch_bounds__(256, 2) void k_pv(
    const bf16_t* __restrict__ U, const bf16_t* __restrict__ Vt,
    float* __restrict__ Out, float* __restrict__ l)
{
    __shared__ bf16_t lds[24576];
    const int lid = blockIdx.x + 8 * blockIdx.y + 128 * blockIdx.z;
    const int b   = lid & 7;
    const int si  = lid >> 3;           // 0..127
    const int xt  = si & 7;
    const int yt  = si >> 3;
    gemm_bt_core<2, 2048, 2048>(lds, U + (size_t)b * 2048 * 2048,
                                Vt + (size_t)b * 1024 * 2048,
                                nullptr, Out + (size_t)b * 2048 * 1024, 1024,
                                l + b * 2048, 0.f, 2048,
                                yt * 128, xt * 128);
}

// fp32 -> bf16 conversion, 4 elems/thread; also zeroes l (16384 floats)
__global__ __launch_bounds__(256) void k_cvt(
    const float* __restrict__ in, bf16_t* __restrict__ out, long ngroups,
    float* __restrict__ l)
{
    long idx    = (long)blockIdx.x * blockDim.x + threadIdx.x;
    long stride = (long)gridDim.x * blockDim.x;
    if (blockIdx.x < 64) l[blockIdx.x * 256 + threadIdx.x] = 0.f;
    for (long i = idx; i < ngroups; i += stride) {
        float4 v = ((const float4*)in)[i];
        bf16x4 o = { (__bf16)v.x, (__bf16)v.y, (__bf16)v.z, (__bf16)v.w };
        ((bf16x4*)out)[i] = o;
    }
}

// fused 3-weight fp32 -> bf16 (z selects source)
__global__ __launch_bounds__(256) void k_cvt3(
    const float* __restrict__ w0, const float* __restrict__ w1,
    const float* __restrict__ w2, bf16_t* __restrict__ out)
{
    const int z = blockIdx.z;
    const float* in = (z == 0) ? w0 : (z == 1) ? w1 : w2;
    bf16_t* o = out + (size_t)z * 1048576;
    long i = (long)blockIdx.x * blockDim.x + threadIdx.x;
    float4 v = ((const float4*)in)[i];
    bf16x4 ov = { (__bf16)v.x, (__bf16)v.y, (__bf16)v.z, (__bf16)v.w };
    ((bf16x4*)o)[i] = ov;
}

// ---------------------------------------------------------------------------

extern "C" void kernel_launch(void* const* d_in, const int* in_sizes, int n_in,
                              void* d_out, int out_size, void* d_ws, size_t ws_size,
                              hipStream_t stream)
{
    const float* x  = (const float*)d_in[0];
    const float* Wq = (const float*)d_in[1];
    const float* bq = (const float*)d_in[2];
    const float* Wk = (const float*)d_in[3];
    const float* bk = (const float*)d_in[4];
    const float* Wv = (const float*)d_in[5];
    const float* bv = (const float*)d_in[6];

    bf16_t* Q    = (bf16_t*)d_ws;              // 16384x1024
    bf16_t* Km   = Q + 16777216;               // 16384x1024
    bf16_t* Vt   = Km + 16777216;              // 8 x 1024x2048
    bf16_t* U    = Vt + 16777216;              // 8 x 2048x2048
    bf16_t* xb   = U;                          // alias: dead before U written
    bf16_t* Wb   = U + 33554432;               // 3 x 1024x1024
    float*  l    = (float*)(Wb + 3145728);     // 16384

    k_cvt<<<dim3(2048), 256, 0, stream>>>(x, xb, 16777216 / 4, l);
    k_cvt3<<<dim3(1024, 1, 3), 256, 0, stream>>>(Wq, Wk, Wv, Wb);
    k_qkv3<<<dim3(8, 128, 3), 256, 0, stream>>>(xb, Wb, Q, Vt, bq, bk, bv);
    k_scores<<<dim3(16, 16, 8), 256, 0, stream>>>(Q, Km, U, l);
    k_pv<<<dim3(8, 16, 8), 256, 0, stream>>>(U, Vt, (float*)d_out, l);
}

// Round 6
// 380.673 us; speedup vs baseline: 1.0856x; 1.0856x over previous
//
#include <hip/hip_runtime.h>
#include <stdint.h>

// Self-attention, B=8, S=2048, D=1024, fp32 in/out, bf16 MFMA compute.
//
// Pipeline:
//   1. k_cvt: x -> xb (bf16), zero l;  k_cvt3: Wq/Wk/Wv -> Wb
//   2. k_qkv3 (z=0,1): Q/K = xb @ W^T + b   (z=2): Vt = (xb @ Wv^T + bv)^T
//   3. k_scores: U = exp((Q @ K^T)/32) bf16 + atomic per-row sums into l
//   4. k_pv   : Out^T-form: Out[b][sq][d] written from C^T = Vt @ U^T,
//               scaled by 1/l[sq]  (fp32 out, float4 stores)
//
// R11 (on the R9 256x256/BK=32/ring-4 core -- R10's 128^2 2-block variant
// REGRESSED 364->413 and is reverted):
//  - Read-hoist: all 12 ds_reads of tile t issued BEFORE B1 (window is
//    after B2(t-1), tile t already published -> no new races; stage(t+3)
//    still writes only the slot of fully-retired tile t-1). Phase 2 is now
//    read-free, so reads(t) overlap the MFMA-p2(t-1) pipe drain and
//    af[4..7] drain under MFMA-p1 via compiler counted lgkmcnt. Model:
//    per-step LDS traffic 128 KB (~500cy) vs MFMA 310cy -> ceiling ~62%
//    MfmaUtil (= m201's measured value); R9's 38% was read/MFMA
//    serialization, which this removes.
//  - pv transposed: C^T[d][sq] = Vt @ U^T (A=Vt LDA=2048, B=U LDB=2048,
//    both already in layout). EPI2 fragment rows become d -> the 4 acc regs
//    are d-consecutive -> coalesced float4 stores (32/thread vs 128 scalar),
//    scale = 1/l[col].
//  - Kept from R9: ring-4 counted-vmcnt(8) schedule (never drains in steady
//    state), XOR chunk swizzle (conflicts 524K ~ 0.22cy/read), batch<->XCD
//    pinning, z-slowest W-pinning, l zeroed in k_cvt, exp-sum softmax.
//
// ws layout:
//   [0,       33.5M)  Q        16384x1024 bf16
//   [33.5M,   67.1M)  K        16384x1024 bf16
//   [67.1M,  100.7M)  Vt       8 x 1024x2048 bf16
//   [100.7M, 167.8M)  U        8 x 2048x2048 bf16  (first half aliases xb)
//   [167.8M, 174.1M)  Wb       3 x 1024x1024 bf16
//   [174.1M, ...)     l        16384 fp32 (attn row sums, atomic)

typedef __bf16 bf16_t;
typedef __bf16 bf16x8 __attribute__((ext_vector_type(8)));
typedef __bf16 bf16x4 __attribute__((ext_vector_type(4)));
typedef float f32x4 __attribute__((ext_vector_type(4)));

__device__ __forceinline__ void gload_lds16(const bf16_t* g, bf16_t* l) {
    __builtin_amdgcn_global_load_lds((const __attribute__((address_space(1))) void*)g,
                                     (__attribute__((address_space(3))) void*)l,
                                     16, 0, 0);
}

// ---------------------------------------------------------------------------
// Core GEMM: C[M,N] = A[M,K] @ B[N,K]^T, bf16 row-major K-contiguous.
// Tile 256x256, BK=32, 512 threads (8 waves 2Mx4N), per-wave 8x4 16x16x32
// MFMA fragments (output 128x64 per wave).
// lds: caller-provided 65536 bf16 (128 KiB): 4 ring buffers of 16384 elems
// (A tile 8192 + B tile 8192). Epilogue (EPI 0/1) reuses it as 128x264 repack.
// EPI: 0 = (+bias[col]) -> bf16 coalesced stores
//      1 = exp(acc*scale) -> bf16 stores + atomic row sums into aux
//      2 = acc*(1/aux[col]) -> fp32 float4 stores to Cf[col*ldc + row]
//          (transposed consumer: row = inner/contiguous dim of Cf)
//      3 = (+bias[col]) -> bf16 TRANSPOSED into Vt[b][col][row]
// ---------------------------------------------------------------------------
template <int EPI, int LDA, int LDB>
__device__ __forceinline__ void gemm256_core(
    bf16_t* __restrict__ lds,
    const bf16_t* __restrict__ A,
    const bf16_t* __restrict__ B,
    bf16_t* __restrict__ Cb, float* __restrict__ Cf, int ldc,
    float* __restrict__ aux, float scale, int K,
    int m0, int n0)
{
    const int t    = threadIdx.x;         // 0..511
    const int lane = t & 63;
    const int wave = t >> 6;              // 0..7
    const int wm   = wave >> 2;           // 0..1  (M half)
    const int wn   = wave & 3;            // 0..3  (N quarter)
    const int lr   = lane & 15;
    const int quad = lane >> 4;

    // Staging: thread t owns 16B slots {t, 512+t} of each tile half.
    // Physical slot s of row r holds logical chunk s ^ ((r>>1)&3) -- the
    // inverse of the read-side XOR (involution), so reads see linear data.
    const int rowS = t >> 2;                       // 0..127
    const int qS   = (t & 3) ^ ((rowS >> 1) & 3);
    const bf16_t* Ag = A + (size_t)(m0 + rowS) * LDA + qS * 8;
    const bf16_t* Bg = B + (size_t)(n0 + rowS) * LDB + qS * 8;
    const int dst0 = t * 8;                        // elems

    // Fragment read offsets (elems): row-major 256x32, slot XOR-swizzled by
    // (lr>>1)&3 -> per-16-lane-quarter start classes (row&1)*4 + slot cover
    // all 8 classes twice -> 2-way bank aliasing only (free).
    const int ko   = (quad ^ ((lr >> 1) & 3)) * 8;
    const int aoff = (wm * 128 + lr) * 32 + ko;
    const int boff = (wn * 64 + lr) * 32 + ko;

    f32x4 acc[8][4];
#pragma unroll
    for (int i = 0; i < 8; i++)
#pragma unroll
        for (int j = 0; j < 4; j++) acc[i][j] = (f32x4){0.f, 0.f, 0.f, 0.f};

    const int T = K >> 5;   // K32-steps (>= 3)

    // Prologue: stage tiles 0,1,2 (12 loads/thread), then require tile 0.
#pragma unroll
    for (int tt = 0; tt < 3; ++tt) {
        bf16_t* Ab = lds + tt * 16384;
        bf16_t* Bb = Ab + 8192;
        const int kt = tt * 32;
        gload_lds16(Ag + kt,                     Ab + dst0);
        gload_lds16(Ag + kt + (size_t)128 * LDA, Ab + 4096 + dst0);
        gload_lds16(Bg + kt,                     Bb + dst0);
        gload_lds16(Bg + kt + (size_t)128 * LDB, Bb + 4096 + dst0);
    }
    asm volatile("s_waitcnt vmcnt(8)" ::: "memory");
    __builtin_amdgcn_s_barrier();
    __builtin_amdgcn_sched_barrier(0);

    for (int tk = 0; tk < T; ++tk) {
        const bf16_t* Ab = lds + (tk & 3) * 16384;
        const bf16_t* Bb = Ab + 8192;
        bf16x8 af[8], bfr[4];
        // ---- ALL 12 ds_reads up-front (tile tk published by B2(tk-1)).
        // These issue while the previous step's MFMA-p2 pipe drains.
#pragma unroll
        for (int j = 0; j < 4; ++j)
            bfr[j] = *(const bf16x8*)(Bb + boff + 512 * j);
#pragma unroll
        for (int i = 0; i < 8; ++i)
            af[i] = *(const bf16x8*)(Ab + aoff + 512 * i);
        __builtin_amdgcn_s_barrier();              // B1 (pacing)
        __builtin_amdgcn_sched_barrier(0);
        __builtin_amdgcn_s_setprio(1);
#pragma unroll
        for (int i = 0; i < 4; ++i)
#pragma unroll
            for (int j = 0; j < 4; ++j)
                acc[i][j] = __builtin_amdgcn_mfma_f32_16x16x32_bf16(af[i], bfr[j], acc[i][j], 0, 0, 0);
        __builtin_amdgcn_s_setprio(0);
        // ---- phase 2 (read-free): stage tile t+3, vmcnt, B2, MFMA i=4..7
        if (tk + 3 < T) {
            bf16_t* An = lds + ((tk + 3) & 3) * 16384;   // = buf of tile t-1 (dead)
            bf16_t* Bn = An + 8192;
            const int kt = (tk + 3) * 32;
            gload_lds16(Ag + kt,                     An + dst0);
            gload_lds16(Ag + kt + (size_t)128 * LDA, An + 4096 + dst0);
            gload_lds16(Bg + kt,                     Bn + dst0);
            gload_lds16(Bg + kt + (size_t)128 * LDB, Bn + 4096 + dst0);
            asm volatile("s_waitcnt vmcnt(8)" ::: "memory");   // tile t+1 confirmed
        } else if (tk + 2 < T) {
            asm volatile("s_waitcnt vmcnt(4)" ::: "memory");
        } else {
            asm volatile("s_waitcnt vmcnt(0)" ::: "memory");
        }
        __builtin_amdgcn_s_barrier();              // B2: tile t+1 published
        __builtin_amdgcn_sched_barrier(0);
        __builtin_amdgcn_s_setprio(1);
#pragma unroll
        for (int i = 4; i < 8; ++i)
#pragma unroll
            for (int j = 0; j < 4; ++j)
                acc[i][j] = __builtin_amdgcn_mfma_f32_16x16x32_bf16(af[i], bfr[j], acc[i][j], 0, 0, 0);
        __builtin_amdgcn_s_setprio(0);
    }

    // Epilogue. C/D frag layout: col = lane&15, row = quad*4 + reg.
    if (EPI == 0 || EPI == 1) {
        // Repack half-by-half (wm half h -> 128x256) in LDS (stride 264),
        // then coalesced 16B stores; EPI1 also accumulates row sums.
#pragma unroll
        for (int h = 0; h < 2; ++h) {
            __syncthreads();
            if (wm == h) {
#pragma unroll
                for (int j = 0; j < 4; ++j) {
                    const int col = wn * 64 + j * 16 + lr;
                    const float bv = (EPI == 0) ? aux[n0 + col] : 0.f;
#pragma unroll
                    for (int i = 0; i < 8; ++i) {
                        const int row = i * 16 + quad * 4;
#pragma unroll
                        for (int r = 0; r < 4; ++r) {
                            float v = (EPI == 0) ? (acc[i][j][r] + bv)
                                                 : __expf(acc[i][j][r] * scale);
                            lds[(row + r) * 264 + col] = (__bf16)v;
                        }
                    }
                }
            }
            __syncthreads();
            const int r2 = t >> 2;            // 0..127
            const int c0 = (t & 3) * 8;       // interleaved col chunks
            float part = 0.f;
#pragma unroll
            for (int c = 0; c < 8; ++c) {
                bf16x8 v = *(const bf16x8*)(lds + r2 * 264 + c0 + c * 32);
                *(bf16x8*)(Cb + (size_t)(m0 + h * 128 + r2) * ldc + n0 + c0 + c * 32) = v;
                if (EPI == 1) {
#pragma unroll
                    for (int e = 0; e < 8; ++e) part += (float)v[e];
                }
            }
            if (EPI == 1) {
                part += __shfl_xor(part, 1);
                part += __shfl_xor(part, 2);
                if ((t & 3) == 0) atomicAdd(aux + m0 + h * 128 + r2, part);
            }
        }
    } else if (EPI == 2) {
        // Transposed consumer: C fragment (row,col) -> Cf[col*ldc + row];
        // the 4 acc regs (r) are row-consecutive -> one float4 store.
#pragma unroll
        for (int j = 0; j < 4; ++j) {
            const int col = n0 + wn * 64 + j * 16 + lr;
            const float s = 1.0f / aux[col];
            float* ccol = Cf + (size_t)col * ldc + m0 + wm * 128;
#pragma unroll
            for (int i = 0; i < 8; ++i) {
                f32x4 v = acc[i][j];
                v[0] *= s; v[1] *= s; v[2] *= s; v[3] *= s;
                *(f32x4*)(ccol + i * 16 + quad * 4) = v;
            }
        }
    } else {
        // EPI 3: transposed write into Vt[b][col][row], rows global = b*2048+s
#pragma unroll
        for (int j = 0; j < 4; ++j) {
            const int col = n0 + wn * 64 + j * 16 + lr;      // d index
            const float bv = aux[col];
#pragma unroll
            for (int i = 0; i < 8; ++i) {
                const int rowg = m0 + wm * 128 + i * 16 + quad * 4;  // global s
                const int b    = rowg >> 11;
                const int s    = rowg & 2047;
                bf16x4 p = { (__bf16)(acc[i][j][0] + bv), (__bf16)(acc[i][j][1] + bv),
                             (__bf16)(acc[i][j][2] + bv), (__bf16)(acc[i][j][3] + bv) };
                *(bf16x4*)(Cb + ((size_t)b << 21) + ((size_t)col << 11) + s) = p;
            }
        }
    }
}

// --------------------------- kernel wrappers -------------------------------

// Q/K/Vt projection, grid (8,96) = 768 blocks. xcd = lid&7; within an XCD,
// x' (weight n-tile, 4) fast, y' (A-strip, 8) middle, z' (matrix) slowest
// -> W_z (2 MB) L2-pinned per phase.
__global__ __launch_bounds__(512, 1) void k_qkv3(
    const bf16_t* __restrict__ xb, const bf16_t* __restrict__ Wb,
    bf16_t* __restrict__ Q, bf16_t* __restrict__ Vt,
    const float* __restrict__ bq, const float* __restrict__ bk,
    const float* __restrict__ bv)
{
    __shared__ bf16_t lds[65536];
    const int lid  = blockIdx.x + 8 * blockIdx.y;
    const int xcd  = lid & 7;
    const int slot = lid >> 3;          // 0..95
    const int z    = slot >> 5;         // 0..2, slowest
    const int rem  = slot & 31;
    const int xt   = rem & 3;           // fast (4 n-tiles)
    const int yt   = xcd * 8 + (rem >> 2);
    if (z < 2) {
        float* bias = (float*)((z == 0) ? bq : bk);
        gemm256_core<0, 1024, 1024>(lds, xb, Wb + (size_t)z * 1048576,
                                    Q + (size_t)z * 16777216, nullptr, 1024,
                                    bias, 0.f, 1024, yt * 256, xt * 256);
    } else {
        gemm256_core<3, 1024, 1024>(lds, xb, Wb + (size_t)2 * 1048576,
                                    Vt, nullptr, 0,
                                    (float*)bv, 0.f, 1024, yt * 256, xt * 256);
    }
}

// scores, grid (8,64) = 512 blocks: batch = lid&7 == XCD -> per-XCD working
// set is one batch's K matrix (4 MB = L2). x-tile fast.
__global__ __launch_bounds__(512, 1) void k_scores(
    const bf16_t* __restrict__ Q, const bf16_t* __restrict__ Km,
    bf16_t* __restrict__ U, float* __restrict__ l)
{
    __shared__ bf16_t lds[65536];
    const int lid = blockIdx.x + 8 * blockIdx.y;
    const int b   = lid & 7;
    const int si  = lid >> 3;           // 0..63
    const int xt  = si & 7;
    const int yt  = si >> 3;
    gemm256_core<1, 1024, 1024>(lds, Q + (size_t)b * 2048 * 1024,
                                Km + (size_t)b * 2048 * 1024,
                                U + (size_t)b * 2048 * 2048, nullptr, 2048,
                                l + b * 2048, 0.03125f, 1024,
                                yt * 256, xt * 256);
}

// PV transposed, grid (8,32) = 256 blocks: C^T[d][sq] = Vt[b] @ U[b]^T,
// A = Vt (M=1024 d-rows, LDA=2048), B = U (N=2048 sq-rows, LDB=2048),
// K = 2048 (sk). Out[b][sq][d] gets coalesced float4 stores, scale 1/l[sq].
// batch = lid&7 == XCD.
__global__ __launch_bounds__(512, 1) void k_pv(
    const bf16_t* __restrict__ U, const bf16_t* __restrict__ Vt,
    float* __restrict__ Out, float* __restrict__ l)
{
    __shared__ bf16_t lds[65536];
    const int lid = blockIdx.x + 8 * blockIdx.y;
    const int b   = lid & 7;
    const int si  = lid >> 3;           // 0..31
    const int xt  = si & 7;             // sq tile (8)
    const int yt  = si >> 3;            // d tile  (4)
    gemm256_core<2, 2048, 2048>(lds, Vt + ((size_t)b << 21),
                                U + (size_t)b * 2048 * 2048,
                                nullptr, Out + (size_t)b * 2048 * 1024, 1024,
                                l + b * 2048, 0.f, 2048,
                                yt * 256, xt * 256);
}

// fp32 -> bf16 conversion, 4 elems/thread; also zeroes l (16384 floats)
__global__ __launch_bounds__(256) void k_cvt(
    const float* __restrict__ in, bf16_t* __restrict__ out, long ngroups,
    float* __restrict__ l)
{
    long idx    = (long)blockIdx.x * blockDim.x + threadIdx.x;
    long stride = (long)gridDim.x * blockDim.x;
    if (blockIdx.x < 64) l[blockIdx.x * 256 + threadIdx.x] = 0.f;
    for (long i = idx; i < ngroups; i += stride) {
        float4 v = ((const float4*)in)[i];
        bf16x4 o = { (__bf16)v.x, (__bf16)v.y, (__bf16)v.z, (__bf16)v.w };
        ((bf16x4*)out)[i] = o;
    }
}

// fused 3-weight fp32 -> bf16 (z selects source)
__global__ __launch_bounds__(256) void k_cvt3(
    const float* __restrict__ w0, const float* __restrict__ w1,
    const float* __restrict__ w2, bf16_t* __restrict__ out)
{
    const int z = blockIdx.z;
    const float* in = (z == 0) ? w0 : (z == 1) ? w1 : w2;
    bf16_t* o = out + (size_t)z * 1048576;
    long i = (long)blockIdx.x * blockDim.x + threadIdx.x;
    float4 v = ((const float4*)in)[i];
    bf16x4 ov = { (__bf16)v.x, (__bf16)v.y, (__bf16)v.z, (__bf16)v.w };
    ((bf16x4*)o)[i] = ov;
}

// ---------------------------------------------------------------------------

extern "C" void kernel_launch(void* const* d_in, const int* in_sizes, int n_in,
                              void* d_out, int out_size, void* d_ws, size_t ws_size,
                              hipStream_t stream)
{
    const float* x  = (const float*)d_in[0];
    const float* Wq = (const float*)d_in[1];
    const float* bq = (const float*)d_in[2];
    const float* Wk = (const float*)d_in[3];
    const float* bk = (const float*)d_in[4];
    const float* Wv = (const float*)d_in[5];
    const float* bv = (const float*)d_in[6];

    bf16_t* Q    = (bf16_t*)d_ws;              // 16384x1024
    bf16_t* Km   = Q + 16777216;               // 16384x1024
    bf16_t* Vt   = Km + 16777216;              // 8 x 1024x2048
    bf16_t* U    = Vt + 16777216;              // 8 x 2048x2048
    bf16_t* xb   = U;                          // alias: dead before U written
    bf16_t* Wb   = U + 33554432;               // 3 x 1024x1024
    float*  l    = (float*)(Wb + 3145728);     // 16384

    k_cvt<<<dim3(2048), 256, 0, stream>>>(x, xb, 16777216 / 4, l);
    k_cvt3<<<dim3(1024, 1, 3), 256, 0, stream>>>(Wq, Wk, Wv, Wb);
    k_qkv3<<<dim3(8, 96), 512, 0, stream>>>(xb, Wb, Q, Vt, bq, bk, bv);
    k_scores<<<dim3(8, 64), 512, 0, stream>>>(Q, Km, U, l);
    k_pv<<<dim3(8, 32), 512, 0, stream>>>(U, Vt, (float*)d_out, l);
}

// Round 9
// 377.094 us; speedup vs baseline: 1.0959x; 1.0095x over previous
//
#include <hip/hip_runtime.h>
#include <stdint.h>

// Self-attention, B=8, S=2048, D=1024, fp32 in/out, bf16 MFMA compute.
//
// Pipeline:
//   1. k_cvt: x -> xb (bf16), zero l;  k_cvt3: Wq/Wk/Wv -> Wb
//   2. k_qkv3 (z=0,1): Q/K = xb @ W^T + b   (z=2): Vt = (xb @ Wv^T + bv)^T
//   3. k_scores: U = exp((Q @ K^T)/32) bf16 + atomic per-row sums into l
//   4. k_pv   : Out[b][sq][d] from C^T = Vt @ U^T, scaled 1/l[sq] (float4)
//
// R12 = R9 core (best: 364us total, qkv 118) + software-pipelined frag reads.
// (Resubmitted twice: R12/R13 benches were infra failures -- source audited
//  for OOB/deadlock, clean; R6 precedent: same error, same source ran clean.)
//  R11 post-mortem: hoisting all reads pre-B1 regressed (38->34 MfmaUtil)
//  -> confirms the stall is lgkm at MFMA-cluster start: in-order wave issues
//  16 MFMAs (~540cy of issue slots), THEN next reads, then B1 -> zero slack.
//  Fix (m196/AITER fine interleave): split each 16-MFMA cluster 8+8 and
//  issue the next frag reads in the gap:
//   p1: [8 MFMA] [read af[4..7](t)] [8 MFMA]       (af2 ready for p2)
//   p2: [8 MFMA] [read af/bfr(t+1) -> naf/nbf] [8 MFMA]  (p1(t+1) ready)
//  Reads get >=270cy slack before consumption; +64 VGPR live frags (free at
//  2 waves/SIMD). Ring-4 safety unchanged: all reads of tile t-1 are
//  completed before their owner wave crosses B1(t) (lgkm-before-MFMA, MFMA
//  issued before B1), and stage(t+3) into buf (t-1)&3 is after B1(t).
//  vmcnt(8) invariant identical to R9. Last-iter next-reads point at the
//  (valid, published) tile T-1 buffer -- harmless.
//  Kept from R11: pv-transposed EPI2 (coalesced float4 out stores).
//  Kept from R9: XOR chunk swizzle (conflicts 524K ~ free), batch<->XCD
//  pinning, z-slowest W-pinning, l zeroed in k_cvt, exp-sum softmax.
//
// ws layout:
//   [0,       33.5M)  Q        16384x1024 bf16
//   [33.5M,   67.1M)  K        16384x1024 bf16
//   [67.1M,  100.7M)  Vt       8 x 1024x2048 bf16
//   [100.7M, 167.8M)  U        8 x 2048x2048 bf16  (first half aliases xb)
//   [167.8M, 174.1M)  Wb       3 x 1024x1024 bf16
//   [174.1M, ...)     l        16384 fp32 (attn row sums, atomic)

typedef __bf16 bf16_t;
typedef __bf16 bf16x8 __attribute__((ext_vector_type(8)));
typedef __bf16 bf16x4 __attribute__((ext_vector_type(4)));
typedef float f32x4 __attribute__((ext_vector_type(4)));

__device__ __forceinline__ void gload_lds16(const bf16_t* g, bf16_t* l) {
    __builtin_amdgcn_global_load_lds((const __attribute__((address_space(1))) void*)g,
                                     (__attribute__((address_space(3))) void*)l,
                                     16, 0, 0);
}

// ---------------------------------------------------------------------------
// Core GEMM: C[M,N] = A[M,K] @ B[N,K]^T, bf16 row-major K-contiguous.
// Tile 256x256, BK=32, 512 threads (8 waves 2Mx4N), per-wave 8x4 16x16x32
// MFMA fragments (output 128x64 per wave).
// lds: caller-provided 65536 bf16 (128 KiB): 4 ring buffers of 16384 elems
// (A tile 8192 + B tile 8192). Epilogue (EPI 0/1) reuses it as 128x264 repack.
// EPI: 0 = (+bias[col]) -> bf16 coalesced stores
//      1 = exp(acc*scale) -> bf16 stores + atomic row sums into aux
//      2 = acc*(1/aux[col]) -> fp32 float4 stores to Cf[col*ldc + row]
//      3 = (+bias[col]) -> bf16 TRANSPOSED into Vt[b][col][row]
// ---------------------------------------------------------------------------
template <int EPI, int LDA, int LDB>
__device__ __forceinline__ void gemm256_core(
    bf16_t* __restrict__ lds,
    const bf16_t* __restrict__ A,
    const bf16_t* __restrict__ B,
    bf16_t* __restrict__ Cb, float* __restrict__ Cf, int ldc,
    float* __restrict__ aux, float scale, int K,
    int m0, int n0)
{
    const int t    = threadIdx.x;         // 0..511
    const int lane = t & 63;
    const int wave = t >> 6;              // 0..7
    const int wm   = wave >> 2;           // 0..1  (M half)
    const int wn   = wave & 3;            // 0..3  (N quarter)
    const int lr   = lane & 15;
    const int quad = lane >> 4;

    // Staging: thread t owns 16B slots {t, 512+t} of each tile half.
    // Physical slot s of row r holds logical chunk s ^ ((r>>1)&3) -- the
    // inverse of the read-side XOR (involution), so reads see linear data.
    const int rowS = t >> 2;                       // 0..127
    const int qS   = (t & 3) ^ ((rowS >> 1) & 3);
    const bf16_t* Ag = A + (size_t)(m0 + rowS) * LDA + qS * 8;
    const bf16_t* Bg = B + (size_t)(n0 + rowS) * LDB + qS * 8;
    const int dst0 = t * 8;                        // elems

    // Fragment read offsets (elems): row-major 256x32, slot XOR-swizzled by
    // (lr>>1)&3 -> per-16-lane-quarter start classes (row&1)*4 + slot cover
    // all 8 classes twice -> 2-way bank aliasing only (free).
    const int ko   = (quad ^ ((lr >> 1) & 3)) * 8;
    const int aoff = (wm * 128 + lr) * 32 + ko;
    const int boff = (wn * 64 + lr) * 32 + ko;

    f32x4 acc[8][4];
#pragma unroll
    for (int i = 0; i < 8; i++)
#pragma unroll
        for (int j = 0; j < 4; j++) acc[i][j] = (f32x4){0.f, 0.f, 0.f, 0.f};

    const int T = K >> 5;   // K32-steps (>= 4)

    // Prologue: stage tiles 0,1,2 (12 loads/thread), require tile 0, then
    // pre-read tile 0's p1 fragments.
#pragma unroll
    for (int tt = 0; tt < 3; ++tt) {
        bf16_t* Ab = lds + tt * 16384;
        bf16_t* Bb = Ab + 8192;
        const int kt = tt * 32;
        gload_lds16(Ag + kt,                     Ab + dst0);
        gload_lds16(Ag + kt + (size_t)128 * LDA, Ab + 4096 + dst0);
        gload_lds16(Bg + kt,                     Bb + dst0);
        gload_lds16(Bg + kt + (size_t)128 * LDB, Bb + 4096 + dst0);
    }
    asm volatile("s_waitcnt vmcnt(8)" ::: "memory");
    __builtin_amdgcn_s_barrier();
    __builtin_amdgcn_sched_barrier(0);

    bf16x8 afA[4], bfA[4];      // current tile's p1 frags (read a phase early)
#pragma unroll
    for (int j = 0; j < 4; ++j)
        bfA[j] = *(const bf16x8*)(lds + 8192 + boff + 512 * j);
#pragma unroll
    for (int i = 0; i < 4; ++i)
        afA[i] = *(const bf16x8*)(lds + aoff + 512 * i);

    for (int tk = 0; tk < T; ++tk) {
        const bf16_t* Ab = lds + (tk & 3) * 16384;
        __builtin_amdgcn_s_barrier();              // B1
        __builtin_amdgcn_sched_barrier(0);
        // ---- p1 first half: i=0,1 (afA/bfA landed >=1 phase ago)
        __builtin_amdgcn_s_setprio(1);
#pragma unroll
        for (int i = 0; i < 2; ++i)
#pragma unroll
            for (int j = 0; j < 4; ++j)
                acc[i][j] = __builtin_amdgcn_mfma_f32_16x16x32_bf16(afA[i], bfA[j], acc[i][j], 0, 0, 0);
        __builtin_amdgcn_s_setprio(0);
        __builtin_amdgcn_sched_barrier(0);
        // ---- mid-p1 reads: af[4..7] of tile t (for p2)
        bf16x8 af2[4];
#pragma unroll
        for (int i = 0; i < 4; ++i)
            af2[i] = *(const bf16x8*)(Ab + aoff + 512 * (4 + i));
        __builtin_amdgcn_sched_barrier(0);
        // ---- p1 second half: i=2,3
        __builtin_amdgcn_s_setprio(1);
#pragma unroll
        for (int i = 2; i < 4; ++i)
#pragma unroll
            for (int j = 0; j < 4; ++j)
                acc[i][j] = __builtin_amdgcn_mfma_f32_16x16x32_bf16(afA[i], bfA[j], acc[i][j], 0, 0, 0);
        __builtin_amdgcn_s_setprio(0);
        // ---- stage tile t+3 into buf of dead tile t-1; counted vmcnt
        if (tk + 3 < T) {
            bf16_t* An = lds + ((tk + 3) & 3) * 16384;
            bf16_t* Bn = An + 8192;
            const int kt = (tk + 3) * 32;
            gload_lds16(Ag + kt,                     An + dst0);
            gload_lds16(Ag + kt + (size_t)128 * LDA, An + 4096 + dst0);
            gload_lds16(Bg + kt,                     Bn + dst0);
            gload_lds16(Bg + kt + (size_t)128 * LDB, Bn + 4096 + dst0);
            asm volatile("s_waitcnt vmcnt(8)" ::: "memory");   // tile t+1 landed
        } else if (tk + 2 < T) {
            asm volatile("s_waitcnt vmcnt(4)" ::: "memory");
        } else {
            asm volatile("s_waitcnt vmcnt(0)" ::: "memory");
        }
        __builtin_amdgcn_s_barrier();              // B2: tile t+1 published
        __builtin_amdgcn_sched_barrier(0);
        // ---- p2 first half: i=4,5
        __builtin_amdgcn_s_setprio(1);
#pragma unroll
        for (int i = 0; i < 2; ++i)
#pragma unroll
            for (int j = 0; j < 4; ++j)
                acc[4 + i][j] = __builtin_amdgcn_mfma_f32_16x16x32_bf16(af2[i], bfA[j], acc[4 + i][j], 0, 0, 0);
        __builtin_amdgcn_s_setprio(0);
        __builtin_amdgcn_sched_barrier(0);
        // ---- mid-p2 reads: p1 frags of tile t+1 (just published by B2)
        const bf16_t* AbN = lds + (((tk + 1 < T) ? (tk + 1) : tk) & 3) * 16384;
        const bf16_t* BbN = AbN + 8192;
        bf16x8 naf[4], nbf[4];
#pragma unroll
        for (int j = 0; j < 4; ++j)
            nbf[j] = *(const bf16x8*)(BbN + boff + 512 * j);
#pragma unroll
        for (int i = 0; i < 4; ++i)
            naf[i] = *(const bf16x8*)(AbN + aoff + 512 * i);
        __builtin_amdgcn_sched_barrier(0);
        // ---- p2 second half: i=6,7
        __builtin_amdgcn_s_setprio(1);
#pragma unroll
        for (int i = 2; i < 4; ++i)
#pragma unroll
            for (int j = 0; j < 4; ++j)
                acc[4 + i][j] = __builtin_amdgcn_mfma_f32_16x16x32_bf16(af2[i], bfA[j], acc[4 + i][j], 0, 0, 0);
        __builtin_amdgcn_s_setprio(0);
#pragma unroll
        for (int i = 0; i < 4; ++i) { afA[i] = naf[i]; bfA[i] = nbf[i]; }
    }

    // Epilogue. C/D frag layout: col = lane&15, row = quad*4 + reg.
    if (EPI == 0 || EPI == 1) {
        // Repack half-by-half (wm half h -> 128x256) in LDS (stride 264),
        // then coalesced 16B stores; EPI1 also accumulates row sums.
#pragma unroll
        for (int h = 0; h < 2; ++h) {
            __syncthreads();
            if (wm == h) {
#pragma unroll
                for (int j = 0; j < 4; ++j) {
                    const int col = wn * 64 + j * 16 + lr;
                    const float bv = (EPI == 0) ? aux[n0 + col] : 0.f;
#pragma unroll
                    for (int i = 0; i < 8; ++i) {
                        const int row = i * 16 + quad * 4;
#pragma unroll
                        for (int r = 0; r < 4; ++r) {
                            float v = (EPI == 0) ? (acc[i][j][r] + bv)
                                                 : __expf(acc[i][j][r] * scale);
                            lds[(row + r) * 264 + col] = (__bf16)v;
                        }
                    }
                }
            }
            __syncthreads();
            const int r2 = t >> 2;            // 0..127
            const int c0 = (t & 3) * 8;       // interleaved col chunks
            float part = 0.f;
#pragma unroll
            for (int c = 0; c < 8; ++c) {
                bf16x8 v = *(const bf16x8*)(lds + r2 * 264 + c0 + c * 32);
                *(bf16x8*)(Cb + (size_t)(m0 + h * 128 + r2) * ldc + n0 + c0 + c * 32) = v;
                if (EPI == 1) {
#pragma unroll
                    for (int e = 0; e < 8; ++e) part += (float)v[e];
                }
            }
            if (EPI == 1) {
                part += __shfl_xor(part, 1);
                part += __shfl_xor(part, 2);
                if ((t & 3) == 0) atomicAdd(aux + m0 + h * 128 + r2, part);
            }
        }
    } else if (EPI == 2) {
        // Transposed consumer: C fragment (row,col) -> Cf[col*ldc + row];
        // the 4 acc regs (r) are row-consecutive -> one float4 store.
#pragma unroll
        for (int j = 0; j < 4; ++j) {
            const int col = n0 + wn * 64 + j * 16 + lr;
            const float s = 1.0f / aux[col];
            float* ccol = Cf + (size_t)col * ldc + m0 + wm * 128;
#pragma unroll
            for (int i = 0; i < 8; ++i) {
                f32x4 v = acc[i][j];
                v[0] *= s; v[1] *= s; v[2] *= s; v[3] *= s;
                *(f32x4*)(ccol + i * 16 + quad * 4) = v;
            }
        }
    } else {
        // EPI 3: transposed write into Vt[b][col][row], rows global = b*2048+s
#pragma unroll
        for (int j = 0; j < 4; ++j) {
            const int col = n0 + wn * 64 + j * 16 + lr;      // d index
            const float bv = aux[col];
#pragma unroll
            for (int i = 0; i < 8; ++i) {
                const int rowg = m0 + wm * 128 + i * 16 + quad * 4;  // global s
                const int b    = rowg >> 11;
                const int s    = rowg & 2047;
                bf16x4 p = { (__bf16)(acc[i][j][0] + bv), (__bf16)(acc[i][j][1] + bv),
                             (__bf16)(acc[i][j][2] + bv), (__bf16)(acc[i][j][3] + bv) };
                *(bf16x4*)(Cb + ((size_t)b << 21) + ((size_t)col << 11) + s) = p;
            }
        }
    }
}

// --------------------------- kernel wrappers -------------------------------

// Q/K/Vt projection, grid (8,96) = 768 blocks. xcd = lid&7; within an XCD,
// x' (weight n-tile, 4) fast, y' (A-strip, 8) middle, z' (matrix) slowest
// -> W_z (2 MB) L2-pinned per phase.
__global__ __launch_bounds__(512, 1) void k_qkv3(
    const bf16_t* __restrict__ xb, const bf16_t* __restrict__ Wb,
    bf16_t* __restrict__ Q, bf16_t* __restrict__ Vt,
    const float* __restrict__ bq, const float* __restrict__ bk,
    const float* __restrict__ bv)
{
    __shared__ bf16_t lds[65536];
    const int lid  = blockIdx.x + 8 * blockIdx.y;
    const int xcd  = lid & 7;
    const int slot = lid >> 3;          // 0..95
    const int z    = slot >> 5;         // 0..2, slowest
    const int rem  = slot & 31;
    const int xt   = rem & 3;           // fast (4 n-tiles)
    const int yt   = xcd * 8 + (rem >> 2);
    if (z < 2) {
        float* bias = (float*)((z == 0) ? bq : bk);
        gemm256_core<0, 1024, 1024>(lds, xb, Wb + (size_t)z * 1048576,
                                    Q + (size_t)z * 16777216, nullptr, 1024,
                                    bias, 0.f, 1024, yt * 256, xt * 256);
    } else {
        gemm256_core<3, 1024, 1024>(lds, xb, Wb + (size_t)2 * 1048576,
                                    Vt, nullptr, 0,
                                    (float*)bv, 0.f, 1024, yt * 256, xt * 256);
    }
}

// scores, grid (8,64) = 512 blocks: batch = lid&7 == XCD -> per-XCD working
// set is one batch's K matrix (4 MB = L2). x-tile fast.
__global__ __launch_bounds__(512, 1) void k_scores(
    const bf16_t* __restrict__ Q, const bf16_t* __restrict__ Km,
    bf16_t* __restrict__ U, float* __restrict__ l)
{
    __shared__ bf16_t lds[65536];
    const int lid = blockIdx.x + 8 * blockIdx.y;
    const int b   = lid & 7;
    const int si  = lid >> 3;           // 0..63
    const int xt  = si & 7;
    const int yt  = si >> 3;
    gemm256_core<1, 1024, 1024>(lds, Q + (size_t)b * 2048 * 1024,
                                Km + (size_t)b * 2048 * 1024,
                                U + (size_t)b * 2048 * 2048, nullptr, 2048,
                                l + b * 2048, 0.03125f, 1024,
                                yt * 256, xt * 256);
}

// PV transposed, grid (8,32) = 256 blocks: C^T[d][sq] = Vt[b] @ U[b]^T,
// A = Vt (M=1024 d-rows, LDA=2048), B = U (N=2048 sq-rows, LDB=2048),
// K = 2048 (sk). Out[b][sq][d] gets coalesced float4 stores, scale 1/l[sq].
// batch = lid&7 == XCD.
__global__ __launch_bounds__(512, 1) void k_pv(
    const bf16_t* __restrict__ U, const bf16_t* __restrict__ Vt,
    float* __restrict__ Out, float* __restrict__ l)
{
    __shared__ bf16_t lds[65536];
    const int lid = blockIdx.x + 8 * blockIdx.y;
    const int b   = lid & 7;
    const int si  = lid >> 3;           // 0..31
    const int xt  = si & 7;             // sq tile (8)
    const int yt  = si >> 3;            // d tile  (4)
    gemm256_core<2, 2048, 2048>(lds, Vt + ((size_t)b << 21),
                                U + (size_t)b * 2048 * 2048,
                                nullptr, Out + (size_t)b * 2048 * 1024, 1024,
                                l + b * 2048, 0.f, 2048,
                                yt * 256, xt * 256);
}

// fp32 -> bf16 conversion, 4 elems/thread; also zeroes l (16384 floats)
__global__ __launch_bounds__(256) void k_cvt(
    const float* __restrict__ in, bf16_t* __restrict__ out, long ngroups,
    float* __restrict__ l)
{
    long idx    = (long)blockIdx.x * blockDim.x + threadIdx.x;
    long stride = (long)gridDim.x * blockDim.x;
    if (blockIdx.x < 64) l[blockIdx.x * 256 + threadIdx.x] = 0.f;
    for (long i = idx; i < ngroups; i += stride) {
        float4 v = ((const float4*)in)[i];
        bf16x4 o = { (__bf16)v.x, (__bf16)v.y, (__bf16)v.z, (__bf16)v.w };
        ((bf16x4*)out)[i] = o;
    }
}

// fused 3-weight fp32 -> bf16 (z selects source)
__global__ __launch_bounds__(256) void k_cvt3(
    const float* __restrict__ w0, const float* __restrict__ w1,
    const float* __restrict__ w2, bf16_t* __restrict__ out)
{
    const int z = blockIdx.z;
    const float* in = (z == 0) ? w0 : (z == 1) ? w1 : w2;
    bf16_t* o = out + (size_t)z * 1048576;
    long i = (long)blockIdx.x * blockDim.x + threadIdx.x;
    float4 v = ((const float4*)in)[i];
    bf16x4 ov = { (__bf16)v.x, (__bf16)v.y, (__bf16)v.z, (__bf16)v.w };
    ((bf16x4*)o)[i] = ov;
}

// ---------------------------------------------------------------------------

extern "C" void kernel_launch(void* const* d_in, const int* in_sizes, int n_in,
                              void* d_out, int out_size, void* d_ws, size_t ws_size,
                              hipStream_t stream)
{
    const float* x  = (const float*)d_in[0];
    const float* Wq = (const float*)d_in[1];
    const float* bq = (const float*)d_in[2];
    const float* Wk = (const float*)d_in[3];
    const float* bk = (const float*)d_in[4];
    const float* Wv = (const float*)d_in[5];
    const float* bv = (const float*)d_in[6];

    bf16_t* Q    = (bf16_t*)d_ws;              // 16384x1024
    bf16_t* Km   = Q + 16777216;               // 16384x1024
    bf16_t* Vt   = Km + 16777216;              // 8 x 1024x2048
    bf16_t* U    = Vt + 16777216;              // 8 x 2048x2048
    bf16_t* xb   = U;                          // alias: dead before U written
    bf16_t* Wb   = U + 33554432;               // 3 x 1024x1024
    float*  l    = (float*)(Wb + 3145728);     // 16384

    k_cvt<<<dim3(2048), 256, 0, stream>>>(x, xb, 16777216 / 4, l);
    k_cvt3<<<dim3(1024, 1, 3), 256, 0, stream>>>(Wq, Wk, Wv, Wb);
    k_qkv3<<<dim3(8, 96), 512, 0, stream>>>(xb, Wb, Q, Vt, bq, bk, bv);
    k_scores<<<dim3(8, 64), 512, 0, stream>>>(Q, Km, U, l);
    k_pv<<<dim3(8, 32), 512, 0, stream>>>(U, Vt, (float*)d_out, l);
}